// Round 10
// baseline (412.885 us; speedup 1.0000x reference)
//
#include <hip/hip_runtime.h>

#define HID     256
#define N_ENT   100000
#define TOT_E   640000
#define HALF_E  320000
#define NSEG    (2 * N_ENT)
#define BN_EPSF 1e-5f
#define SCAN_ELEMS 1024
#define NBLK_SCAN  ((NSEG + SCAN_ELEMS - 1) / SCAN_ELEMS)   // 196

typedef short bf16x8 __attribute__((ext_vector_type(8)));
typedef short bf16x4 __attribute__((ext_vector_type(4)));
typedef float f32x4  __attribute__((ext_vector_type(4)));

__device__ __forceinline__ short f2b(float f) {
    union { float f; unsigned u; } c; c.f = f;
    unsigned u = c.u;
    u += 0x7FFF + ((u >> 16) & 1);          // round-to-nearest-even
    return (short)(u >> 16);
}
__device__ __forceinline__ float b2f(short b) {
    union { unsigned u; float f; } c;
    c.u = ((unsigned)(unsigned short)b) << 16;
    return c.f;
}

// ================= prep: f32->bf16 (x, rel) + zero offs/stats + wcat =================
#define NX8 (N_ENT * HID / 8)
#define NR8 (50 * HID / 8)
#define CONV_BLOCKS ((NX8 + NR8 + 255) / 256)
__global__ void prep_kernel(const float* __restrict__ x, short* __restrict__ xh,
                            const float* __restrict__ rel, short* __restrict__ relh,
                            const float* __restrict__ w_in, const float* __restrict__ w_out,
                            const float* __restrict__ w_loop, const float* __restrict__ loop_rel,
                            short* __restrict__ WT,
                            int* __restrict__ offs, float* __restrict__ stats) {
    int bid = blockIdx.x;
    int tid = threadIdx.x;
    if (bid < CONV_BLOCKS) {
        int i = bid * 256 + tid;
        if (i < NSEG) offs[i] = 0;
        if (i < 512) stats[i] = 0.f;
        const float* src; short* dst; int idx;
        if (i < NX8) { src = x; dst = xh; idx = i; }
        else if (i < NX8 + NR8) { src = rel; dst = relh; idx = i - NX8; }
        else return;
        const float4* p = (const float4*)(src + (size_t)idx * 8);
        float4 v0 = p[0], v1 = p[1];
        bf16x8 pk;
        pk[0]=f2b(v0.x); pk[1]=f2b(v0.y); pk[2]=f2b(v0.z); pk[3]=f2b(v0.w);
        pk[4]=f2b(v1.x); pk[5]=f2b(v1.y); pk[6]=f2b(v1.z); pk[7]=f2b(v1.w);
        *(bf16x8*)(dst + (size_t)idx * 8) = pk;
    } else {
        // wcat: WT[n][k] = bf16 of [w_in; w_out; diag(loop_rel) w_loop]^T
        int n = bid - CONV_BLOCKS;          // 0..255
        int t = tid;
        float v0 = w_in  [(size_t)t * HID + n];
        float v1 = w_out [(size_t)t * HID + n];
        float v2 = w_loop[(size_t)t * HID + n] * loop_rel[t];
        short* row = WT + (size_t)n * 768;
        row[t]       = f2b(v0);
        row[256 + t] = f2b(v1);
        row[512 + t] = f2b(v2);
    }
}

// ================= CSR build =================
__global__ void hist_kernel(const int* __restrict__ ei, int* __restrict__ offs) {
    int j = blockIdx.x * 256 + threadIdx.x;
    if (j >= TOT_E) return;
    int seg = ei[j] + ((j < HALF_E) ? 0 : N_ENT);
    atomicAdd(&offs[seg], 1);
}

// scan1 also emits rnorm = rsqrt(count)
__global__ __launch_bounds__(256) void scan1(int* __restrict__ offs, int* __restrict__ bsums,
                                             float* __restrict__ rnorm) {
    __shared__ int tsum[256];
    int b = blockIdx.x, t = threadIdx.x;
    int base = b * SCAN_ELEMS + t * 4;
    int v[4] = {0, 0, 0, 0};
    if (base + 3 < NSEG) {
        int4 lv = *(const int4*)(offs + base);
        v[0] = lv.x; v[1] = lv.y; v[2] = lv.z; v[3] = lv.w;
    } else {
        for (int i = 0; i < 4; ++i) if (base + i < NSEG) v[i] = offs[base + i];
    }
    #pragma unroll
    for (int i = 0; i < 4; ++i)
        if (base + i < NSEG)
            rnorm[base + i] = (v[i] > 0) ? rsqrtf((float)v[i]) : 0.f;
    tsum[t] = v[0] + v[1] + v[2] + v[3];
    __syncthreads();
    for (int d = 1; d < 256; d <<= 1) {
        int val = (t >= d) ? tsum[t - d] : 0;
        __syncthreads();
        tsum[t] += val;
        __syncthreads();
    }
    int run = (t == 0) ? 0 : tsum[t - 1];
    if (t == 255) bsums[b] = tsum[255];
    int w[4];
    for (int i = 0; i < 4; ++i) { w[i] = run; run += v[i]; }
    if (base + 3 < NSEG) *(int4*)(offs + base) = make_int4(w[0], w[1], w[2], w[3]);
    else for (int i = 0; i < 4; ++i) if (base + i < NSEG) offs[base + i] = w[i];
}

// scan3 with scan2 fused: every block re-scans bsums (196 elems) in LDS.
__global__ __launch_bounds__(256) void scan3f(int* __restrict__ offs, const int* __restrict__ bsums) {
    __shared__ int tmp[256];
    int b = blockIdx.x, t = threadIdx.x;
    tmp[t] = (t < NBLK_SCAN) ? bsums[t] : 0;
    __syncthreads();
    for (int d = 1; d < 256; d <<= 1) {
        int val = (t >= d) ? tmp[t - d] : 0;
        __syncthreads();
        tmp[t] += val;
        __syncthreads();
    }
    int add = (b == 0) ? 0 : tmp[b - 1];
    int base = b * SCAN_ELEMS + t * 4;
    if (base + 3 < NSEG) {
        int4 v = *(int4*)(offs + base);
        v.x += add; v.y += add; v.z += add; v.w += add;
        *(int4*)(offs + base) = v;
    } else {
        for (int i = 0; i < 4; ++i) if (base + i < NSEG) offs[base + i] += add;
    }
}

// fill8: elist8[pos] = {col | type<<17, norm}; mutates offs[s] -> segment END.
__global__ void fill8_kernel(const int* __restrict__ ei, const int* __restrict__ et,
                             int* __restrict__ offs, const float* __restrict__ rnorm,
                             int2* __restrict__ elist8) {
    int j = blockIdx.x * 256 + threadIdx.x;
    if (j >= TOT_E) return;
    int hb  = (j < HALF_E) ? 0 : N_ENT;
    int seg = ei[j] + hb;
    int col = ei[TOT_E + j];
    float norm = rnorm[seg] * rnorm[hb + col];
    int pos = atomicAdd(&offs[seg], 1);
    elist8[pos] = make_int2(col | (et[j] << 17), __float_as_int(norm));
}

// ================= fused gather + MFMA GEMM =================
// block = 64 output rows, 256 thr = 4 waves.
// Phase s0: wave w gathers in-segments of its 16 rows -> As[64][256] (bf16, swizzled)
//           then 4 K-steps of MFMA vs WT[:, 0:256] (w_in).
// Phase s1: same with out-segments vs WT[:, 256:512] (w_out).
// Phase s2: copy xh rows -> As, 4 K-steps vs WT[:, 512:768] (loop-folded w_loop).
// acc tiles never touch global memory. Epilogue: out/3 (bf16|f32) + fused BN stats.
// As granule swizzle: slot(g, row) = (g & 24) | ((g ^ row) & 7)   (g = 16B granule 0..31)
template <bool BF16OUT>
__global__ __launch_bounds__(256) void fused_gg(
        const short* __restrict__ xh, const short* __restrict__ relh,
        const int* __restrict__ offs, const int2* __restrict__ elist8,
        const short* __restrict__ WT,
        float* __restrict__ out, short* __restrict__ outh, float* __restrict__ stats)
{
    __shared__ __align__(16) short As[64 * 256];   // 32 KB
    __shared__ __align__(16) short Bs[256 * 64];   // 32 KB
    const int tid = threadIdx.x;
    const int l   = tid & 63;
    const int wid = tid >> 6;
    const int r0  = blockIdx.x * 64;
    const int lr  = l & 15;
    const int lg  = l >> 4;
    const int sg  = tid & 7;
    const int sr  = tid >> 3;

    f32x4 acc[4][4];
    #pragma unroll
    for (int i = 0; i < 4; ++i)
        #pragma unroll
        for (int j = 0; j < 4; ++j)
            acc[i][j] = (f32x4){0.f, 0.f, 0.f, 0.f};

    for (int phase = 0; phase < 3; ++phase) {
        // ---- fill As (gather or copy); As was fully consumed by previous phase ----
        if (phase < 2) {
            const int hb = (phase == 0) ? 0 : N_ENT;
            #pragma unroll 1
            for (int rr = 0; rr < 16; ++rr) {
                const int r  = wid * 16 + rr;
                const int gr = r0 + r;
                float ax0=0.f, ay0=0.f, az0=0.f, aw0=0.f;
                float ax1=0.f, ay1=0.f, az1=0.f, aw1=0.f;
                if (gr < N_ENT) {
                    int seg   = hb + gr;
                    int start = (seg == 0) ? 0 : offs[seg - 1];
                    int end   = offs[seg];
                    int e = start;
                    for (; e + 2 <= end; e += 2) {
                        int2 p0 = elist8[e];
                        int2 p1 = elist8[e + 1];
                        int   c0 = p0.x & 0x1FFFF, t0 = p0.x >> 17;
                        float n0 = __int_as_float(p0.y);
                        int   c1 = p1.x & 0x1FFFF, t1 = p1.x >> 17;
                        float n1 = __int_as_float(p1.y);
                        bf16x4 xv0 = *(const bf16x4*)(xh   + (size_t)c0 * HID + l * 4);
                        bf16x4 rv0 = *(const bf16x4*)(relh + (size_t)t0 * HID + l * 4);
                        bf16x4 xv1 = *(const bf16x4*)(xh   + (size_t)c1 * HID + l * 4);
                        bf16x4 rv1 = *(const bf16x4*)(relh + (size_t)t1 * HID + l * 4);
                        ax0 += b2f(xv0[0]) * b2f(rv0[0]) * n0;
                        ay0 += b2f(xv0[1]) * b2f(rv0[1]) * n0;
                        az0 += b2f(xv0[2]) * b2f(rv0[2]) * n0;
                        aw0 += b2f(xv0[3]) * b2f(rv0[3]) * n0;
                        ax1 += b2f(xv1[0]) * b2f(rv1[0]) * n1;
                        ay1 += b2f(xv1[1]) * b2f(rv1[1]) * n1;
                        az1 += b2f(xv1[2]) * b2f(rv1[2]) * n1;
                        aw1 += b2f(xv1[3]) * b2f(rv1[3]) * n1;
                    }
                    if (e < end) {
                        int2 p = elist8[e];
                        int   c = p.x & 0x1FFFF, t = p.x >> 17;
                        float n = __int_as_float(p.y);
                        bf16x4 xv = *(const bf16x4*)(xh   + (size_t)c * HID + l * 4);
                        bf16x4 rv = *(const bf16x4*)(relh + (size_t)t * HID + l * 4);
                        ax0 += b2f(xv[0]) * b2f(rv[0]) * n;
                        ay0 += b2f(xv[1]) * b2f(rv[1]) * n;
                        az0 += b2f(xv[2]) * b2f(rv[2]) * n;
                        aw0 += b2f(xv[3]) * b2f(rv[3]) * n;
                    }
                }
                // write row r: lane covers bytes [l*8, l*8+8) -> granule l>>1, half l&1
                int g    = l >> 1;
                int slot = (g & 24) | ((g ^ r) & 7);
                bf16x4 pk;
                pk[0] = f2b(ax0 + ax1); pk[1] = f2b(ay0 + ay1);
                pk[2] = f2b(az0 + az1); pk[3] = f2b(aw0 + aw1);
                *(bf16x4*)&As[r * 256 + slot * 8 + (l & 1) * 4] = pk;
            }
        } else {
            // copy xh rows into As (coalesced bf16x8)
            #pragma unroll
            for (int h = 0; h < 2; ++h) {
                int r  = sr + 32 * h;
                int gr = r0 + r;
                #pragma unroll
                for (int c = 0; c < 4; ++c) {
                    bf16x8 v = {0,0,0,0,0,0,0,0};
                    if (gr < N_ENT)
                        v = *(const bf16x8*)(xh + (size_t)gr * HID + (c * 8 + sg) * 8);
                    int slot = c * 8 + ((sg ^ r) & 7);
                    *(bf16x8*)&As[r * 256 + slot * 8] = v;
                }
            }
        }
        __syncthreads();

        // ---- 4 K-steps: stage Bs from WT, MFMA vs As window ----
        for (int ktl = 0; ktl < 4; ++ktl) {
            const int ksg = phase * 256 + ktl * 64;
            #pragma unroll
            for (int i = 0; i < 8; ++i) {
                int n = sr + 32 * i;
                bf16x8 w = *(const bf16x8*)(WT + (size_t)n * 768 + ksg + sg * 8);
                *(bf16x8*)&Bs[n * 64 + ((sg ^ (n & 7)) << 3)] = w;
            }
            __syncthreads();
            #pragma unroll
            for (int kc = 0; kc < 2; ++kc) {
                const int gsel = kc * 4 + lg;
                bf16x8 af[4];
                #pragma unroll
                for (int i = 0; i < 4; ++i) {
                    int r = 16 * i + lr;
                    af[i] = *(const bf16x8*)&As[r * 256 + (ktl * 8 + ((gsel ^ r) & 7)) * 8];
                }
                #pragma unroll
                for (int j = 0; j < 4; ++j) {
                    int n = wid * 64 + 16 * j + lr;
                    bf16x8 bfr = *(const bf16x8*)&Bs[n * 64 + ((gsel ^ (n & 7)) << 3)];
                    #pragma unroll
                    for (int i = 0; i < 4; ++i)
                        acc[i][j] = __builtin_amdgcn_mfma_f32_16x16x32_bf16(
                                        af[i], bfr, acc[i][j], 0, 0, 0);
                }
            }
            __syncthreads();
        }
    }

    // ---- epilogue: write out/3, fused BN partial stats ----
    const float third = 1.f / 3.f;
    float s[4]  = {0.f, 0.f, 0.f, 0.f};
    float sq[4] = {0.f, 0.f, 0.f, 0.f};
    #pragma unroll
    for (int i = 0; i < 4; ++i) {
        #pragma unroll
        for (int v = 0; v < 4; ++v) {
            int grow = r0 + 16 * i + lg * 4 + v;
            if (grow < N_ENT) {
                #pragma unroll
                for (int j = 0; j < 4; ++j) {
                    float val = acc[i][j][v] * third;
                    int col = wid * 64 + 16 * j + lr;
                    if (BF16OUT) outh[(size_t)grow * HID + col] = f2b(val);
                    else         out [(size_t)grow * HID + col] = val;
                    s[j] += val; sq[j] += val * val;
                }
            }
        }
    }
    #pragma unroll
    for (int j = 0; j < 4; ++j) {
        s[j]  += __shfl_xor(s[j], 16);  s[j]  += __shfl_xor(s[j], 32);
        sq[j] += __shfl_xor(sq[j], 16); sq[j] += __shfl_xor(sq[j], 32);
    }
    if (lg == 0) {
        #pragma unroll
        for (int j = 0; j < 4; ++j) {
            int c = wid * 64 + 16 * j + lr;
            atomicAdd(&stats[c], s[j]);
            atomicAdd(&stats[HID + c], sq[j]);
        }
    }
}

// ================= batchnorm apply + relout (fused launch) =================
#define BN_BLOCKS 1024
__global__ void bn_relout_h(const short* __restrict__ outh, float* __restrict__ out,
                            const float* __restrict__ stats,
                            const float* __restrict__ bnw, const float* __restrict__ bnb,
                            const float* __restrict__ rel_embed, const float* __restrict__ w_rel,
                            float* __restrict__ rel_out) {
    if (blockIdx.x < BN_BLOCKS) {
        const float invN = 1.f / (float)N_ENT;
        const int total8 = N_ENT * (HID / 8);
        for (int i = blockIdx.x * 256 + threadIdx.x; i < total8; i += BN_BLOCKS * 256) {
            int c = (i & 31) * 8;
            bf16x8 v = *(const bf16x8*)(outh + (size_t)i * 8);
            float r[8];
            #pragma unroll
            for (int k = 0; k < 8; ++k) {
                float mean = stats[c + k] * invN;
                float var  = stats[HID + c + k] * invN - mean * mean;
                float sc   = rsqrtf(var + BN_EPSF) * bnw[c + k];
                float sh   = bnb[c + k] - mean * sc;
                r[k] = b2f(v[k]) * sc + sh;
            }
            float4* dst = (float4*)(out + (size_t)i * 8);
            dst[0] = make_float4(r[0], r[1], r[2], r[3]);
            dst[1] = make_float4(r[4], r[5], r[6], r[7]);
        }
    } else {
        __shared__ float row[HID];
        int r = blockIdx.x - BN_BLOCKS;    // 0..49
        int c = threadIdx.x;
        row[c] = rel_embed[(size_t)r * HID + c];
        __syncthreads();
        float sum = 0.f;
        #pragma unroll 8
        for (int k = 0; k < HID; ++k) sum += row[k] * w_rel[(size_t)k * HID + c];
        rel_out[(size_t)r * HID + c] = sum;
    }
}

// f32 fallback BN (no outh)
__global__ void bn_relout_f(float* __restrict__ out, const float* __restrict__ stats,
                            const float* __restrict__ bnw, const float* __restrict__ bnb,
                            const float* __restrict__ rel_embed, const float* __restrict__ w_rel,
                            float* __restrict__ rel_out) {
    if (blockIdx.x < BN_BLOCKS) {
        const float invN = 1.f / (float)N_ENT;
        const int total4 = N_ENT * (HID / 4);
        for (int i = blockIdx.x * 256 + threadIdx.x; i < total4; i += BN_BLOCKS * 256) {
            int c = (i & 63) * 4;
            float4 v = *(float4*)(out + (size_t)i * 4);
            #pragma unroll
            for (int k = 0; k < 4; ++k) {
                float mean = stats[c + k] * invN;
                float var  = stats[HID + c + k] * invN - mean * mean;
                float sc   = rsqrtf(var + BN_EPSF) * bnw[c + k];
                float sh   = bnb[c + k] - mean * sc;
                float* comp = (k == 0) ? &v.x : (k == 1) ? &v.y : (k == 2) ? &v.z : &v.w;
                *comp = (*comp) * sc + sh;
            }
            *(float4*)(out + (size_t)i * 4) = v;
        }
    } else {
        __shared__ float row[HID];
        int r = blockIdx.x - BN_BLOCKS;
        int c = threadIdx.x;
        row[c] = rel_embed[(size_t)r * HID + c];
        __syncthreads();
        float sum = 0.f;
        #pragma unroll 8
        for (int k = 0; k < HID; ++k) sum += row[k] * w_rel[(size_t)k * HID + c];
        rel_out[(size_t)r * HID + c] = sum;
    }
}

extern "C" void kernel_launch(void* const* d_in, const int* in_sizes, int n_in,
                              void* d_out, int out_size, void* d_ws, size_t ws_size,
                              hipStream_t stream) {
    const float* x        = (const float*)d_in[0];
    const int*   ei       = (const int*)d_in[1];
    const int*   et       = (const int*)d_in[2];
    const float* rel      = (const float*)d_in[3];
    const float* w_loop   = (const float*)d_in[4];
    const float* w_in     = (const float*)d_in[5];
    const float* w_out    = (const float*)d_in[6];
    const float* w_rel    = (const float*)d_in[7];
    const float* loop_rel = (const float*)d_in[8];
    const float* bnw      = (const float*)d_in[9];
    const float* bnb      = (const float*)d_in[10];

    float* out     = (float*)d_out;
    float* rel_out = out + (size_t)N_ENT * HID;

    const size_t XH_B   = (size_t)N_ENT * HID * 2;   // 51.2 MB
    const size_t OFFS_B = (size_t)NSEG * 4;
    const size_t EL8_B  = (size_t)TOT_E * 8;
    const size_t RN_B   = (size_t)NSEG * 4;
    const size_t RELH_B = (size_t)50 * HID * 2;
    const size_t WT_B   = (size_t)256 * 768 * 2;     // 384 KB
    const size_t base_need = XH_B + OFFS_B + EL8_B + RN_B
                           + 256 * 4 + 512 * 4 + RELH_B + WT_B;
    const size_t OUTH_B = (size_t)N_ENT * HID * 2;
    const bool   have_outh = (ws_size >= base_need + OUTH_B);

    char* w = (char*)d_ws;
    short* xh     = (short*)w;              w += XH_B;
    int*   offs   = (int*)w;                w += OFFS_B;
    int2*  elist8 = (int2*)w;               w += EL8_B;
    float* rnorm  = (float*)w;              w += RN_B;
    int*   bsums  = (int*)w;                w += 256 * 4;
    float* stats  = (float*)w;              w += 512 * 4;
    short* relh   = (short*)w;              w += RELH_B;
    short* WT     = (short*)w;              w += WT_B;
    short* outh   = (short*)w;

    // 1. convert + zero offs/stats + wcat
    prep_kernel<<<CONV_BLOCKS + 256, 256, 0, stream>>>(x, xh, rel, relh,
                                                       w_in, w_out, w_loop, loop_rel,
                                                       WT, offs, stats);
    // 2-5. CSR build
    hist_kernel<<<TOT_E / 256, 256, 0, stream>>>(ei, offs);
    scan1<<<NBLK_SCAN, 256, 0, stream>>>(offs, bsums, rnorm);
    scan3f<<<NBLK_SCAN, 256, 0, stream>>>(offs, bsums);
    fill8_kernel<<<TOT_E / 256, 256, 0, stream>>>(ei, et, offs, rnorm, elist8);
    // 6. fused gather + GEMM (+ BN stats); 7. BN apply + relout
    if (have_outh) {
        fused_gg<true><<<(N_ENT + 63) / 64, 256, 0, stream>>>(
            xh, relh, offs, elist8, WT, out, outh, stats);
        bn_relout_h<<<BN_BLOCKS + 50, 256, 0, stream>>>(outh, out, stats, bnw, bnb,
                                                        rel, w_rel, rel_out);
    } else {
        fused_gg<false><<<(N_ENT + 63) / 64, 256, 0, stream>>>(
            xh, relh, offs, elist8, WT, out, outh, stats);
        bn_relout_f<<<BN_BLOCKS + 50, 256, 0, stream>>>(out, stats, bnw, bnb,
                                                        rel, w_rel, rel_out);
    }
}

// Round 11
// 308.146 us; speedup vs baseline: 1.3399x; 1.3399x over previous
//
#include <hip/hip_runtime.h>

#define HID     256
#define N_ENT   100000
#define TOT_E   640000
#define HALF_E  320000
#define NSEG    (2 * N_ENT)
#define BN_EPSF 1e-5f
#define SCAN_ELEMS 1024
#define NBLK_SCAN  ((NSEG + SCAN_ELEMS - 1) / SCAN_ELEMS)   // 196

typedef short bf16x8 __attribute__((ext_vector_type(8)));
typedef short bf16x4 __attribute__((ext_vector_type(4)));
typedef float f32x4  __attribute__((ext_vector_type(4)));

__device__ __forceinline__ short f2b(float f) {
    union { float f; unsigned u; } c; c.f = f;
    unsigned u = c.u;
    u += 0x7FFF + ((u >> 16) & 1);          // round-to-nearest-even
    return (short)(u >> 16);
}
__device__ __forceinline__ float b2f(short b) {
    union { unsigned u; float f; } c;
    c.u = ((unsigned)(unsigned short)b) << 16;
    return c.f;
}

// ================= prep: f32->bf16 (x, rel) + zero offs/stats + wcat =================
#define NX8 (N_ENT * HID / 8)
#define NR8 (50 * HID / 8)
#define CONV_BLOCKS ((NX8 + NR8 + 255) / 256)
__global__ void prep_kernel(const float* __restrict__ x, short* __restrict__ xh,
                            const float* __restrict__ rel, short* __restrict__ relh,
                            const float* __restrict__ w_in, const float* __restrict__ w_out,
                            const float* __restrict__ w_loop, const float* __restrict__ loop_rel,
                            short* __restrict__ WT,
                            int* __restrict__ offs, float* __restrict__ stats) {
    int bid = blockIdx.x;
    int tid = threadIdx.x;
    if (bid < CONV_BLOCKS) {
        int i = bid * 256 + tid;
        if (i < NSEG) offs[i] = 0;
        if (i < 512) stats[i] = 0.f;
        const float* src; short* dst; int idx;
        if (i < NX8) { src = x; dst = xh; idx = i; }
        else if (i < NX8 + NR8) { src = rel; dst = relh; idx = i - NX8; }
        else return;
        const float4* p = (const float4*)(src + (size_t)idx * 8);
        float4 v0 = p[0], v1 = p[1];
        bf16x8 pk;
        pk[0]=f2b(v0.x); pk[1]=f2b(v0.y); pk[2]=f2b(v0.z); pk[3]=f2b(v0.w);
        pk[4]=f2b(v1.x); pk[5]=f2b(v1.y); pk[6]=f2b(v1.z); pk[7]=f2b(v1.w);
        *(bf16x8*)(dst + (size_t)idx * 8) = pk;
    } else {
        // wcat: WT[n][k] = bf16 of [w_in; w_out; diag(loop_rel) w_loop]^T
        int n = bid - CONV_BLOCKS;          // 0..255
        int t = tid;
        float v0 = w_in  [(size_t)t * HID + n];
        float v1 = w_out [(size_t)t * HID + n];
        float v2 = w_loop[(size_t)t * HID + n] * loop_rel[t];
        short* row = WT + (size_t)n * 768;
        row[t]       = f2b(v0);
        row[256 + t] = f2b(v1);
        row[512 + t] = f2b(v2);
    }
}

// ================= CSR build =================
__global__ void hist_kernel(const int* __restrict__ ei, int* __restrict__ offs) {
    int j = blockIdx.x * 256 + threadIdx.x;
    if (j >= TOT_E) return;
    int seg = ei[j] + ((j < HALF_E) ? 0 : N_ENT);
    atomicAdd(&offs[seg], 1);
}

// scan1 also emits rnorm = rsqrt(count)
__global__ __launch_bounds__(256) void scan1(int* __restrict__ offs, int* __restrict__ bsums,
                                             float* __restrict__ rnorm) {
    __shared__ int tsum[256];
    int b = blockIdx.x, t = threadIdx.x;
    int base = b * SCAN_ELEMS + t * 4;
    int v[4] = {0, 0, 0, 0};
    if (base + 3 < NSEG) {
        int4 lv = *(const int4*)(offs + base);
        v[0] = lv.x; v[1] = lv.y; v[2] = lv.z; v[3] = lv.w;
    } else {
        for (int i = 0; i < 4; ++i) if (base + i < NSEG) v[i] = offs[base + i];
    }
    #pragma unroll
    for (int i = 0; i < 4; ++i)
        if (base + i < NSEG)
            rnorm[base + i] = (v[i] > 0) ? rsqrtf((float)v[i]) : 0.f;
    tsum[t] = v[0] + v[1] + v[2] + v[3];
    __syncthreads();
    for (int d = 1; d < 256; d <<= 1) {
        int val = (t >= d) ? tsum[t - d] : 0;
        __syncthreads();
        tsum[t] += val;
        __syncthreads();
    }
    int run = (t == 0) ? 0 : tsum[t - 1];
    if (t == 255) bsums[b] = tsum[255];
    int w[4];
    for (int i = 0; i < 4; ++i) { w[i] = run; run += v[i]; }
    if (base + 3 < NSEG) *(int4*)(offs + base) = make_int4(w[0], w[1], w[2], w[3]);
    else for (int i = 0; i < 4; ++i) if (base + i < NSEG) offs[base + i] = w[i];
}

// scan3 with scan2 fused: every block re-scans bsums (196 elems) in LDS.
__global__ __launch_bounds__(256) void scan3f(int* __restrict__ offs, const int* __restrict__ bsums) {
    __shared__ int tmp[256];
    int b = blockIdx.x, t = threadIdx.x;
    tmp[t] = (t < NBLK_SCAN) ? bsums[t] : 0;
    __syncthreads();
    for (int d = 1; d < 256; d <<= 1) {
        int val = (t >= d) ? tmp[t - d] : 0;
        __syncthreads();
        tmp[t] += val;
        __syncthreads();
    }
    int add = (b == 0) ? 0 : tmp[b - 1];
    int base = b * SCAN_ELEMS + t * 4;
    if (base + 3 < NSEG) {
        int4 v = *(int4*)(offs + base);
        v.x += add; v.y += add; v.z += add; v.w += add;
        *(int4*)(offs + base) = v;
    } else {
        for (int i = 0; i < 4; ++i) if (base + i < NSEG) offs[base + i] += add;
    }
}

// fill8: elist8[pos] = {col | type<<17, norm}; mutates offs[s] -> segment END.
__global__ void fill8_kernel(const int* __restrict__ ei, const int* __restrict__ et,
                             int* __restrict__ offs, const float* __restrict__ rnorm,
                             int2* __restrict__ elist8) {
    int j = blockIdx.x * 256 + threadIdx.x;
    if (j >= TOT_E) return;
    int hb  = (j < HALF_E) ? 0 : N_ENT;
    int seg = ei[j] + hb;
    int col = ei[TOT_E + j];
    float norm = rnorm[seg] * rnorm[hb + col];
    int pos = atomicAdd(&offs[seg], 1);
    elist8[pos] = make_int2(col | (et[j] << 17), __float_as_int(norm));
}

// ================= gather: one wave (64 lanes x bf16x4) per segment, unroll x2 =================
// round-4 proven config: VGPR ~20, occupancy ~71%
__global__ __launch_bounds__(256) void gather_h(
        const short* __restrict__ xh, const short* __restrict__ relh,
        const int* __restrict__ offs, const int2* __restrict__ elist8,
        short* __restrict__ accA, short* __restrict__ accB) {
    int s = blockIdx.x * 4 + (threadIdx.x >> 6);
    int lane = threadIdx.x & 63;
    int start = (s == 0) ? 0 : offs[s - 1];
    int end   = offs[s];
    float ax0=0.f, ay0=0.f, az0=0.f, aw0=0.f;
    float ax1=0.f, ay1=0.f, az1=0.f, aw1=0.f;
    int e = start;
    for (; e + 2 <= end; e += 2) {
        int2 p0 = elist8[e];
        int2 p1 = elist8[e + 1];
        int   c0 = p0.x & 0x1FFFF, t0 = p0.x >> 17;
        float n0 = __int_as_float(p0.y);
        int   c1 = p1.x & 0x1FFFF, t1 = p1.x >> 17;
        float n1 = __int_as_float(p1.y);
        bf16x4 xv0 = *(const bf16x4*)(xh   + (size_t)c0 * HID + lane * 4);
        bf16x4 rv0 = *(const bf16x4*)(relh + (size_t)t0 * HID + lane * 4);
        bf16x4 xv1 = *(const bf16x4*)(xh   + (size_t)c1 * HID + lane * 4);
        bf16x4 rv1 = *(const bf16x4*)(relh + (size_t)t1 * HID + lane * 4);
        ax0 += b2f(xv0[0]) * b2f(rv0[0]) * n0;
        ay0 += b2f(xv0[1]) * b2f(rv0[1]) * n0;
        az0 += b2f(xv0[2]) * b2f(rv0[2]) * n0;
        aw0 += b2f(xv0[3]) * b2f(rv0[3]) * n0;
        ax1 += b2f(xv1[0]) * b2f(rv1[0]) * n1;
        ay1 += b2f(xv1[1]) * b2f(rv1[1]) * n1;
        az1 += b2f(xv1[2]) * b2f(rv1[2]) * n1;
        aw1 += b2f(xv1[3]) * b2f(rv1[3]) * n1;
    }
    if (e < end) {
        int2 p = elist8[e];
        int   c = p.x & 0x1FFFF, t = p.x >> 17;
        float n = __int_as_float(p.y);
        bf16x4 xv = *(const bf16x4*)(xh   + (size_t)c * HID + lane * 4);
        bf16x4 rv = *(const bf16x4*)(relh + (size_t)t * HID + lane * 4);
        ax0 += b2f(xv[0]) * b2f(rv[0]) * n;
        ay0 += b2f(xv[1]) * b2f(rv[1]) * n;
        az0 += b2f(xv[2]) * b2f(rv[2]) * n;
        aw0 += b2f(xv[3]) * b2f(rv[3]) * n;
    }
    int hb = (s >= N_ENT) ? N_ENT : 0;
    short* dst = ((s >= N_ENT) ? accB : accA) + (size_t)(s - hb) * HID + lane * 4;
    bf16x4 pk;
    pk[0] = f2b(ax0 + ax1); pk[1] = f2b(ay0 + ay1);
    pk[2] = f2b(az0 + az1); pk[3] = f2b(aw0 + aw1);
    *(bf16x4*)dst = pk;
}

// ================= MFMA GEMM: exact round-4 structure (88.7 us), templated output =================
// 256 thr = 4 waves; tile 64 rows x 256 cols; BK=64; 12 K-steps, 2 barriers each.
// No launch_bounds cap (round-9 lesson: forcing 128 regs spills acc to scratch).
template <bool BF16OUT>
__global__ __launch_bounds__(256) void gemm_mfma_h(
        const short* __restrict__ accA, const short* __restrict__ accB,
        const short* __restrict__ xh, const short* __restrict__ WT,
        float* __restrict__ out, short* __restrict__ outh, float* __restrict__ stats)
{
    __shared__ __align__(16) short As[64 * 64];    // 8 KB
    __shared__ __align__(16) short Bs[256 * 64];   // 32 KB
    const int tid = threadIdx.x;
    const int l   = tid & 63;
    const int wid = tid >> 6;
    const int r0  = blockIdx.x * 64;
    const int lr  = l & 15;
    const int lg  = l >> 4;

    f32x4 acc[4][4];
    #pragma unroll
    for (int i = 0; i < 4; ++i)
        #pragma unroll
        for (int j = 0; j < 4; ++j)
            acc[i][j] = (f32x4){0.f, 0.f, 0.f, 0.f};

    const int sg = tid & 7;
    const int sr = tid >> 3;

    for (int kt = 0; kt < 12; ++kt) {
        const int src = kt >> 2;
        const short* Ap = (src == 0) ? accA : ((src == 1) ? accB : xh);
        const int ksg = kt * 64;
        const int ksl = (kt & 3) * 64;
        __syncthreads();
        #pragma unroll
        for (int h = 0; h < 2; ++h) {
            int r  = sr + 32 * h;
            int gr = r0 + r;
            bf16x8 v = {0,0,0,0,0,0,0,0};
            if (gr < N_ENT) v = *(const bf16x8*)(Ap + (size_t)gr * HID + ksl + sg * 8);
            *(bf16x8*)&As[r * 64 + ((sg ^ (r & 7)) << 3)] = v;
        }
        #pragma unroll
        for (int i = 0; i < 8; ++i) {
            int n = sr + 32 * i;
            bf16x8 w = *(const bf16x8*)(WT + (size_t)n * 768 + ksg + sg * 8);
            *(bf16x8*)&Bs[n * 64 + ((sg ^ (n & 7)) << 3)] = w;
        }
        __syncthreads();
        #pragma unroll
        for (int kc = 0; kc < 2; ++kc) {
            const int gsel = kc * 4 + lg;
            bf16x8 af[4], bfr[4];
            #pragma unroll
            for (int i = 0; i < 4; ++i) {
                int r = 16 * i + lr;
                af[i] = *(const bf16x8*)&As[r * 64 + ((gsel ^ (r & 7)) << 3)];
            }
            #pragma unroll
            for (int j = 0; j < 4; ++j) {
                int n = wid * 64 + 16 * j + lr;
                bfr[j] = *(const bf16x8*)&Bs[n * 64 + ((gsel ^ (n & 7)) << 3)];
            }
            #pragma unroll
            for (int i = 0; i < 4; ++i)
                #pragma unroll
                for (int j = 0; j < 4; ++j)
                    acc[i][j] = __builtin_amdgcn_mfma_f32_16x16x32_bf16(
                                    af[i], bfr[j], acc[i][j], 0, 0, 0);
        }
    }

    const float third = 1.f / 3.f;
    float s[4]  = {0.f, 0.f, 0.f, 0.f};
    float sq[4] = {0.f, 0.f, 0.f, 0.f};
    #pragma unroll
    for (int i = 0; i < 4; ++i) {
        #pragma unroll
        for (int v = 0; v < 4; ++v) {
            int grow = r0 + 16 * i + lg * 4 + v;
            if (grow < N_ENT) {
                #pragma unroll
                for (int j = 0; j < 4; ++j) {
                    float val = acc[i][j][v] * third;
                    int col = wid * 64 + 16 * j + lr;
                    if (BF16OUT) outh[(size_t)grow * HID + col] = f2b(val);
                    else         out [(size_t)grow * HID + col] = val;
                    s[j] += val; sq[j] += val * val;
                }
            }
        }
    }
    #pragma unroll
    for (int j = 0; j < 4; ++j) {
        s[j]  += __shfl_xor(s[j], 16);  s[j]  += __shfl_xor(s[j], 32);
        sq[j] += __shfl_xor(sq[j], 16); sq[j] += __shfl_xor(sq[j], 32);
    }
    if (lg == 0) {
        #pragma unroll
        for (int j = 0; j < 4; ++j) {
            int c = wid * 64 + 16 * j + lr;
            atomicAdd(&stats[c], s[j]);
            atomicAdd(&stats[HID + c], sq[j]);
        }
    }
}

// ================= batchnorm apply + relout (fused launch) =================
#define BN_BLOCKS 1024
__global__ void bn_relout_h(const short* __restrict__ outh, float* __restrict__ out,
                            const float* __restrict__ stats,
                            const float* __restrict__ bnw, const float* __restrict__ bnb,
                            const float* __restrict__ rel_embed, const float* __restrict__ w_rel,
                            float* __restrict__ rel_out) {
    if (blockIdx.x < BN_BLOCKS) {
        const float invN = 1.f / (float)N_ENT;
        const int total8 = N_ENT * (HID / 8);
        for (int i = blockIdx.x * 256 + threadIdx.x; i < total8; i += BN_BLOCKS * 256) {
            int c = (i & 31) * 8;
            bf16x8 v = *(const bf16x8*)(outh + (size_t)i * 8);
            float r[8];
            #pragma unroll
            for (int k = 0; k < 8; ++k) {
                float mean = stats[c + k] * invN;
                float var  = stats[HID + c + k] * invN - mean * mean;
                float sc   = rsqrtf(var + BN_EPSF) * bnw[c + k];
                float sh   = bnb[c + k] - mean * sc;
                r[k] = b2f(v[k]) * sc + sh;
            }
            float4* dst = (float4*)(out + (size_t)i * 8);
            dst[0] = make_float4(r[0], r[1], r[2], r[3]);
            dst[1] = make_float4(r[4], r[5], r[6], r[7]);
        }
    } else {
        __shared__ float row[HID];
        int r = blockIdx.x - BN_BLOCKS;    // 0..49
        int c = threadIdx.x;
        row[c] = rel_embed[(size_t)r * HID + c];
        __syncthreads();
        float sum = 0.f;
        #pragma unroll 8
        for (int k = 0; k < HID; ++k) sum += row[k] * w_rel[(size_t)k * HID + c];
        rel_out[(size_t)r * HID + c] = sum;
    }
}

// f32 fallback BN (no outh)
__global__ void bn_relout_f(float* __restrict__ out, const float* __restrict__ stats,
                            const float* __restrict__ bnw, const float* __restrict__ bnb,
                            const float* __restrict__ rel_embed, const float* __restrict__ w_rel,
                            float* __restrict__ rel_out) {
    if (blockIdx.x < BN_BLOCKS) {
        const float invN = 1.f / (float)N_ENT;
        const int total4 = N_ENT * (HID / 4);
        for (int i = blockIdx.x * 256 + threadIdx.x; i < total4; i += BN_BLOCKS * 256) {
            int c = (i & 63) * 4;
            float4 v = *(float4*)(out + (size_t)i * 4);
            #pragma unroll
            for (int k = 0; k < 4; ++k) {
                float mean = stats[c + k] * invN;
                float var  = stats[HID + c + k] * invN - mean * mean;
                float sc   = rsqrtf(var + BN_EPSF) * bnw[c + k];
                float sh   = bnb[c + k] - mean * sc;
                float* comp = (k == 0) ? &v.x : (k == 1) ? &v.y : (k == 2) ? &v.z : &v.w;
                *comp = (*comp) * sc + sh;
            }
            *(float4*)(out + (size_t)i * 4) = v;
        }
    } else {
        __shared__ float row[HID];
        int r = blockIdx.x - BN_BLOCKS;
        int c = threadIdx.x;
        row[c] = rel_embed[(size_t)r * HID + c];
        __syncthreads();
        float sum = 0.f;
        #pragma unroll 8
        for (int k = 0; k < HID; ++k) sum += row[k] * w_rel[(size_t)k * HID + c];
        rel_out[(size_t)r * HID + c] = sum;
    }
}

extern "C" void kernel_launch(void* const* d_in, const int* in_sizes, int n_in,
                              void* d_out, int out_size, void* d_ws, size_t ws_size,
                              hipStream_t stream) {
    const float* x        = (const float*)d_in[0];
    const int*   ei       = (const int*)d_in[1];
    const int*   et       = (const int*)d_in[2];
    const float* rel      = (const float*)d_in[3];
    const float* w_loop   = (const float*)d_in[4];
    const float* w_in     = (const float*)d_in[5];
    const float* w_out    = (const float*)d_in[6];
    const float* w_rel    = (const float*)d_in[7];
    const float* loop_rel = (const float*)d_in[8];
    const float* bnw      = (const float*)d_in[9];
    const float* bnb      = (const float*)d_in[10];

    float* out     = (float*)d_out;
    float* rel_out = out + (size_t)N_ENT * HID;

    const size_t XH_B   = (size_t)N_ENT * HID * 2;   // 51.2 MB
    const size_t ACC_B  = (size_t)N_ENT * HID * 2;
    const size_t OFFS_B = (size_t)NSEG * 4;
    const size_t EL8_B  = (size_t)TOT_E * 8;
    const size_t RN_B   = (size_t)NSEG * 4;
    const size_t RELH_B = (size_t)50 * HID * 2;
    const size_t WT_B   = (size_t)256 * 768 * 2;     // 384 KB
    const size_t base_need = XH_B + 2 * ACC_B + OFFS_B + EL8_B + RN_B
                           + 256 * 4 + 512 * 4 + RELH_B + WT_B;
    const size_t OUTH_B = (size_t)N_ENT * HID * 2;
    const bool   have_outh = (ws_size >= base_need + OUTH_B);

    char* w = (char*)d_ws;
    short* xh     = (short*)w;              w += XH_B;
    short* accA_h = (short*)w;              w += ACC_B;
    short* accB_h = (short*)w;              w += ACC_B;
    int*   offs   = (int*)w;                w += OFFS_B;
    int2*  elist8 = (int2*)w;               w += EL8_B;
    float* rnorm  = (float*)w;              w += RN_B;
    int*   bsums  = (int*)w;                w += 256 * 4;
    float* stats  = (float*)w;              w += 512 * 4;
    short* relh   = (short*)w;              w += RELH_B;
    short* WT     = (short*)w;              w += WT_B;
    short* outh   = (short*)w;

    // 1. convert + zero offs/stats + wcat
    prep_kernel<<<CONV_BLOCKS + 256, 256, 0, stream>>>(x, xh, rel, relh,
                                                       w_in, w_out, w_loop, loop_rel,
                                                       WT, offs, stats);
    // 2-5. CSR build
    hist_kernel<<<TOT_E / 256, 256, 0, stream>>>(ei, offs);
    scan1<<<NBLK_SCAN, 256, 0, stream>>>(offs, bsums, rnorm);
    scan3f<<<NBLK_SCAN, 256, 0, stream>>>(offs, bsums);
    fill8_kernel<<<TOT_E / 256, 256, 0, stream>>>(ei, et, offs, rnorm, elist8);
    // 6. gather (round-4 proven config)
    gather_h<<<NSEG / 4, 256, 0, stream>>>(xh, relh, offs, elist8, accA_h, accB_h);
    // 7. GEMM (round-4 proven config) + fused BN stats; 8. BN apply + relout
    if (have_outh) {
        gemm_mfma_h<true><<<(N_ENT + 63) / 64, 256, 0, stream>>>(
            accA_h, accB_h, xh, WT, out, outh, stats);
        bn_relout_h<<<BN_BLOCKS + 50, 256, 0, stream>>>(outh, out, stats, bnw, bnb,
                                                        rel, w_rel, rel_out);
    } else {
        gemm_mfma_h<false><<<(N_ENT + 63) / 64, 256, 0, stream>>>(
            accA_h, accB_h, xh, WT, out, outh, stats);
        bn_relout_f<<<BN_BLOCKS + 50, 256, 0, stream>>>(out, stats, bnw, bnb,
                                                        rel, w_rel, rel_out);
    }
}